// Round 15
// baseline (547.254 us; speedup 1.0000x reference)
//
#include <hip/hip_runtime.h>
#include <hip/hip_bf16.h>
#include <math.h>
#include <type_traits>

typedef __bf16 bf16_t;
typedef __bf16 bf16x8 __attribute__((ext_vector_type(8)));
typedef __bf16 bf16x4 __attribute__((ext_vector_type(4)));
typedef float  f32x4  __attribute__((ext_vector_type(4)));
typedef float  f32x16 __attribute__((ext_vector_type(16)));
typedef unsigned int u32x2 __attribute__((ext_vector_type(2)));
typedef unsigned int u32x4 __attribute__((ext_vector_type(4)));

#define MFMA_BF16(a, b, c) __builtin_amdgcn_mfma_f32_16x16x32_bf16(a, b, c, 0, 0, 0)
#define MFMA32_BF16(a, b, c) __builtin_amdgcn_mfma_f32_32x32x16_bf16(a, b, c, 0, 0, 0)

#if __has_builtin(__builtin_amdgcn_exp2f)
__device__ __forceinline__ float fast_exp2(float x) { return __builtin_amdgcn_exp2f(x); }
#else
__device__ __forceinline__ float fast_exp2(float x) { return exp2f(x); }
#endif

// NaN-safe tanh-form GELU: g = v - v/(exp2(k*u)+1), u = v(1+0.044715 v^2).
__device__ __forceinline__ float fast_gelu(float v) {
  const float u = v * (1.f + 0.044715f * v * v);
  const float tt = fast_exp2(2.3022078f * u);
  return v - v / (tt + 1.f);
}

// async global->LDS, 16B per lane; LDS dest is wave-uniform base + lane*16
__device__ __forceinline__ void gload_lds16(const bf16_t* g, bf16_t* l) {
  __builtin_amdgcn_global_load_lds(
      (const __attribute__((address_space(1))) void*)g,
      (__attribute__((address_space(3))) void*)l, 16, 0, 0);
}

// ---------------------------------------------------------------------------
// Merged transpose + fp32 -> bf16 convert for all 4 weights (one launch).
// ---------------------------------------------------------------------------
__global__ __launch_bounds__(256) void sa_transpose4(const float* __restrict__ s0, bf16_t* __restrict__ d0,
                                                     const float* __restrict__ s1, bf16_t* __restrict__ d1,
                                                     const float* __restrict__ s2, bf16_t* __restrict__ d2,
                                                     const float* __restrict__ s3, bf16_t* __restrict__ d3) {
  __shared__ bf16_t tile[64][65];
  const int bid = blockIdx.x;
  const float* in; bf16_t* out; int K, N, local;
  if (bid < 768)       { in = s0; out = d0; K = 1024; N = 3072; local = bid; }
  else if (bid < 1024) { in = s1; out = d1; K = 1024; N = 1024; local = bid - 768; }
  else if (bid < 2048) { in = s2; out = d2; K = 1024; N = 4096; local = bid - 1024; }
  else                 { in = s3; out = d3; K = 4096; N = 1024; local = bid - 2048; }
  const int nx = N >> 6;
  const int n0 = (local % nx) * 64, k0 = (local / nx) * 64;
  const int t = threadIdx.x;
#pragma unroll
  for (int i = 0; i < 16; ++i) {
    int idx = t + i * 256;
    int r = idx >> 6, c = idx & 63;
    tile[r][c] = (bf16_t)in[(size_t)(k0 + r) * N + n0 + c];
  }
  __syncthreads();
#pragma unroll
  for (int i = 0; i < 16; ++i) {
    int idx = t + i * 256;
    int r = idx >> 6, c = idx & 63;
    out[(size_t)(n0 + r) * K + k0 + c] = tile[c][r];
  }
}

// ---------------------------------------------------------------------------
// LayerNorm over D=1024 (fp32 input), one block per row. bf16 out.
// ---------------------------------------------------------------------------
__global__ __launch_bounds__(256) void sa_layernorm(const float* __restrict__ in,
                                                    const float* __restrict__ gamma,
                                                    const float* __restrict__ beta,
                                                    bf16_t* __restrict__ out_bf) {
  const int row = blockIdx.x, t = threadIdx.x;
  const float4 v = *(const float4*)(in + (size_t)row * 1024 + t * 4);
  float s  = v.x + v.y + v.z + v.w;
  float ss = v.x * v.x + v.y * v.y + v.z * v.z + v.w * v.w;
#pragma unroll
  for (int m = 1; m < 64; m <<= 1) {
    s  += __shfl_xor(s, m, 64);
    ss += __shfl_xor(ss, m, 64);
  }
  __shared__ float red[8];
  const int w = t >> 6, lane = t & 63;
  if (lane == 0) { red[w] = s; red[4 + w] = ss; }
  __syncthreads();
  s  = red[0] + red[1] + red[2] + red[3];
  ss = red[4] + red[5] + red[6] + red[7];
  const float mu   = s * (1.f / 1024.f);
  const float rstd = rsqrtf(ss * (1.f / 1024.f) - mu * mu + 1e-5f);
  const float4 gv = *(const float4*)(gamma + t * 4);
  const float4 bv = *(const float4*)(beta + t * 4);
  bf16x4 ob = { (bf16_t)((v.x - mu) * rstd * gv.x + bv.x),
                (bf16_t)((v.y - mu) * rstd * gv.y + bv.y),
                (bf16_t)((v.z - mu) * rstd * gv.z + bv.z),
                (bf16_t)((v.w - mu) * rstd * gv.w + bv.w) };
  *(bf16x4*)(out_bf + (size_t)row * 1024 + t * 4) = ob;
}

// ---------------------------------------------------------------------------
// LayerNorm over D=1024 (bf16 input), one block per row. bf16 out.
// ---------------------------------------------------------------------------
__global__ __launch_bounds__(256) void sa_layernorm_b(const bf16_t* __restrict__ in,
                                                      const float* __restrict__ gamma,
                                                      const float* __restrict__ beta,
                                                      bf16_t* __restrict__ out_bf) {
  const int row = blockIdx.x, t = threadIdx.x;
  const bf16x4 iv = *(const bf16x4*)(in + (size_t)row * 1024 + t * 4);
  const float v0 = (float)iv[0], v1 = (float)iv[1], v2 = (float)iv[2], v3 = (float)iv[3];
  float s  = v0 + v1 + v2 + v3;
  float ss = v0 * v0 + v1 * v1 + v2 * v2 + v3 * v3;
#pragma unroll
  for (int m = 1; m < 64; m <<= 1) {
    s  += __shfl_xor(s, m, 64);
    ss += __shfl_xor(ss, m, 64);
  }
  __shared__ float red[8];
  const int w = t >> 6, lane = t & 63;
  if (lane == 0) { red[w] = s; red[4 + w] = ss; }
  __syncthreads();
  s  = red[0] + red[1] + red[2] + red[3];
  ss = red[4] + red[5] + red[6] + red[7];
  const float mu   = s * (1.f / 1024.f);
  const float rstd = rsqrtf(ss * (1.f / 1024.f) - mu * mu + 1e-5f);
  const float4 gv = *(const float4*)(gamma + t * 4);
  const float4 bv = *(const float4*)(beta + t * 4);
  bf16x4 ob = { (bf16_t)((v0 - mu) * rstd * gv.x + bv.x),
                (bf16_t)((v1 - mu) * rstd * gv.y + bv.y),
                (bf16_t)((v2 - mu) * rstd * gv.z + bv.z),
                (bf16_t)((v3 - mu) * rstd * gv.w + bv.w) };
  *(bf16x4*)(out_bf + (size_t)row * 1024 + t * 4) = ob;
}

// ---------------------------------------------------------------------------
// GEMM v6: A-operand DIRECT FROM GLOBAL (L1/L2-served; frags are contiguous
// 16B), only B staged through LDS (dbuf 32KB) -> halves LDS traffic (the
// measured 30%-MfmaUtil cap was LDS-read-BW: U*410 B/cy vs ~112 B/cy
// sustainable) and allows 3 blocks/CU for latency hiding.
// 128x128 tile, BK=64, 4 waves (2x2), 2-phase schedule (stage-early),
// 8x8 supertile XCD decode, zero-conflict XOR swizzle on B (both sides).
// EPI: 0 = QKV split (Q scaled by 0.125*log2e; V transposed [bh][d][L]),
//      1 = bf16 store, 2 = fast-GELU->bf16, 3 = fp32 store + bf16 residual.
// Requires gridDim.x % 8 == 0 and gridDim.y == 64. NT even.
// ---------------------------------------------------------------------------
template <int EPI>
__global__ __launch_bounds__(256, 3) void sa_gemm6(const bf16_t* __restrict__ A,
                                                   const bf16_t* __restrict__ Bt,
                                                   const float* __restrict__ bias,
                                                   int K, int N,
                                                   float* __restrict__ fout,
                                                   bf16_t* __restrict__ bfout,
                                                   const bf16_t* __restrict__ res,
                                                   bf16_t* __restrict__ qb,
                                                   bf16_t* __restrict__ kb,
                                                   bf16_t* __restrict__ vb) {
  __shared__ __attribute__((aligned(16))) bf16_t Bs[2][128][64];   // 32 KB total

  const int gx = gridDim.x;
  const int flat = blockIdx.y * gx + blockIdx.x;
  const int c = flat & 7;
  const int local = flat >> 3;
  const int sg = local >> 6;
  const int rem = local & 63;
  const int by = c * 8 + (rem >> 3);
  const int bx = sg * 8 + (rem & 7);

  const int m0 = by * 128, n0 = bx * 128;
  const int t = threadIdx.x;
  const int w = t >> 6, lane = t & 63;
  const int wr = w >> 1, wc = w & 1;
  const int fr = lane & 15, fq = lane >> 4;
  const int swz = fr & 7;
  const int srow = lane >> 3;
  const int scol = ((lane & 7) ^ srow) * 8;
  const int NT = K >> 6;

  const f32x4 fzero = { 0.f, 0.f, 0.f, 0.f };
  f32x4 acc[4][4];
#pragma unroll
  for (int mi = 0; mi < 4; ++mi)
#pragma unroll
    for (int ni = 0; ni < 4; ++ni) acc[mi][ni] = fzero;

  // per-wave A-frag row pointers (contiguous 16B frags in global)
  const bf16_t* arow[4];
#pragma unroll
  for (int mi = 0; mi < 4; ++mi)
    arow[mi] = A + (size_t)(m0 + wr * 64 + mi * 16 + fr) * K + fq * 8;

  auto stageB = [&](int tt, int sb) {
#pragma unroll
    for (int i = 0; i < 4; ++i) {
      const int ch = w * 4 + i;
      const int row = ch * 8 + srow;
      gload_lds16(Bt + (size_t)(n0 + row) * K + tt * 64 + scol, &Bs[sb][ch * 8][0]);
    }
  };

  auto compute = [&](auto curc, int tt) {
    constexpr int cur = decltype(curc)::value;
    bf16x8 af[4][2], bfr[4][2];
#pragma unroll
    for (int mi = 0; mi < 4; ++mi)
#pragma unroll
      for (int kk = 0; kk < 2; ++kk)
        af[mi][kk] = *(const bf16x8*)(arow[mi] + tt * 64 + kk * 32);
#pragma unroll
    for (int ni = 0; ni < 4; ++ni)
#pragma unroll
      for (int kk = 0; kk < 2; ++kk)
        bfr[ni][kk] = *(const bf16x8*)&Bs[cur][wc * 64 + ni * 16 + fr][((kk * 4 + fq) ^ swz) * 8];
    __builtin_amdgcn_s_setprio(1);
#pragma unroll
    for (int kk = 0; kk < 2; ++kk)
#pragma unroll
      for (int mi = 0; mi < 4; ++mi)
#pragma unroll
        for (int ni = 0; ni < 4; ++ni)
          acc[mi][ni] = MFMA_BF16(af[mi][kk], bfr[ni][kk], acc[mi][ni]);
    __builtin_amdgcn_s_setprio(0);
  };

  stageB(0, 0);
  __syncthreads();

  for (int tt = 0; tt < NT; tt += 2) {
    stageB(tt + 1, 1);                       // NT even -> tt+1 < NT always
    compute(std::integral_constant<int, 0>{}, tt);
    __syncthreads();
    if (tt + 2 < NT) stageB(tt + 2, 0);
    compute(std::integral_constant<int, 1>{}, tt + 1);
    __syncthreads();
  }

#pragma unroll
  for (int ni = 0; ni < 4; ++ni) {
    const int n = n0 + wc * 64 + ni * 16 + fr;
    const float bn = bias[n];
#pragma unroll
    for (int mi = 0; mi < 4; ++mi) {
      const int mbase = m0 + wr * 64 + mi * 16 + fq * 4;
      float vv[4];
#pragma unroll
      for (int r = 0; r < 4; ++r) vv[r] = acc[mi][ni][r] + bn;
      if constexpr (EPI == 0) {
        const int which = n >> 10;
        const int hh = (n >> 6) & 15;
        const int d = n & 63;
        const int b = mbase >> 11, l = mbase & 2047;
        if (which == 0) {
#pragma unroll
          for (int r = 0; r < 4; ++r)
            qb[((size_t)(b * 16 + hh) * 2048 + l + r) * 64 + d] =
                (bf16_t)(vv[r] * (0.125f * 1.44269504088896340736f));
        } else if (which == 1) {
#pragma unroll
          for (int r = 0; r < 4; ++r)
            kb[((size_t)(b * 16 + hh) * 2048 + l + r) * 64 + d] = (bf16_t)vv[r];
        } else {
          bf16x4 pv = { (bf16_t)vv[0], (bf16_t)vv[1], (bf16_t)vv[2], (bf16_t)vv[3] };
          *(bf16x4*)(vb + ((size_t)(b * 16 + hh) * 64 + d) * 2048 + l) = pv;
        }
      } else if constexpr (EPI == 1) {
#pragma unroll
        for (int r = 0; r < 4; ++r)
          bfout[(size_t)(mbase + r) * N + n] = (bf16_t)vv[r];
      } else if constexpr (EPI == 2) {
#pragma unroll
        for (int r = 0; r < 4; ++r)
          bfout[(size_t)(mbase + r) * N + n] = (bf16_t)fast_gelu(vv[r]);
      } else {
#pragma unroll
        for (int r = 0; r < 4; ++r)
          fout[(size_t)(mbase + r) * N + n] = vv[r] + (float)res[(size_t)(mbase + r) * N + n];
      }
    }
  }
}

// ---------------------------------------------------------------------------
// Flash attention v4 (r14, unchanged): 32x32x16 MFMA, in-register P,
// fixed-reference softmax, double-buffered LDS via global_load_lds with
// pre-swizzled source (rule #21), XCD-swizzled grid.
// ---------------------------------------------------------------------------
__global__ __launch_bounds__(256) void sa_attn32(const bf16_t* __restrict__ qb,
                                                 const bf16_t* __restrict__ kb,
                                                 const bf16_t* __restrict__ vb,
                                                 bf16_t* __restrict__ out) {
  __shared__ __attribute__((aligned(16))) bf16_t Ks[2][64][64];   // 16 KB
  __shared__ __attribute__((aligned(16))) bf16_t Vt[2][64][64];   // 16 KB

  const int nwg = gridDim.x * gridDim.y;            // 1024
  const int flat = blockIdx.y * gridDim.x + blockIdx.x;
  const int wg = (flat & 7) * (nwg >> 3) + (flat >> 3);
  const int qblk = wg & 15, bh = wg >> 4;

  const int t = threadIdx.x, wq = t >> 6, lane = t & 63;
  const int q31 = lane & 31, hi = lane >> 5;
  const int qx = q31 & 7;
  const size_t base = (size_t)bh * 2048 * 64;

  const int srow = lane >> 3;
  const int sunit = (lane & 7) ^ srow;

  const bf16_t* qrow = qb + base + (size_t)(qblk * 128 + wq * 32 + q31) * 64 + hi * 8;
  bf16x8 qf[4];
#pragma unroll
  for (int c = 0; c < 4; ++c) qf[c] = *(const bf16x8*)(qrow + c * 16);

  auto STAGE = [&](int kv0, int buf) {
#pragma unroll
    for (int i = 0; i < 2; ++i) {
      const int rb = wq * 16 + i * 8;
      gload_lds16(kb + base + (size_t)(kv0 + rb + srow) * 64 + sunit * 8,
                  &Ks[buf][rb][0]);
      gload_lds16(vb + base + (size_t)(rb + srow) * 2048 + kv0 + sunit * 8,
                  &Vt[buf][rb][0]);
    }
  };

  f32x16 o0, o1, la0, la1;
#pragma unroll
  for (int i = 0; i < 16; ++i) { o0[i] = 0.f; o1[i] = 0.f; la0[i] = 0.f; la1[i] = 0.f; }

  auto COMPUTE = [&](auto bufc) {
    constexpr int buf = decltype(bufc)::value;
    f32x16 s0, s1;
#pragma unroll
    for (int i = 0; i < 16; ++i) { s0[i] = 0.f; s1[i] = 0.f; }
    __builtin_amdgcn_s_setprio(1);
#pragma unroll
    for (int c = 0; c < 4; ++c) {
      bf16x8 ka0 = *(const bf16x8*)&Ks[buf][q31]     [((2 * c + hi) ^ qx) * 8];
      bf16x8 ka1 = *(const bf16x8*)&Ks[buf][q31 + 32][((2 * c + hi) ^ qx) * 8];
      s0 = MFMA32_BF16(ka0, qf[c], s0);
      s1 = MFMA32_BF16(ka1, qf[c], s1);
    }
    __builtin_amdgcn_s_setprio(0);

#pragma unroll
    for (int i = 0; i < 16; ++i) s0[i] = fast_exp2(s0[i]);
#pragma unroll
    for (int i = 0; i < 16; ++i) s1[i] = fast_exp2(s1[i]);
    la0 += s0;
    la1 += s1;

    u32x4 pw[4];
#define PACK_CHUNK(c, SB, off)                                                      \
    {                                                                               \
      unsigned int x0, x1, y0, y1;                                                  \
      asm("v_cvt_pk_bf16_f32 %0, %1, %2" : "=v"(x0) : "v"(SB[off+0]), "v"(SB[off+1])); \
      asm("v_cvt_pk_bf16_f32 %0, %1, %2" : "=v"(x1) : "v"(SB[off+2]), "v"(SB[off+3])); \
      asm("v_cvt_pk_bf16_f32 %0, %1, %2" : "=v"(y0) : "v"(SB[off+4]), "v"(SB[off+5])); \
      asm("v_cvt_pk_bf16_f32 %0, %1, %2" : "=v"(y1) : "v"(SB[off+6]), "v"(SB[off+7])); \
      u32x2 r0 = __builtin_amdgcn_permlane32_swap(x0, y0, false, false);            \
      u32x2 r1 = __builtin_amdgcn_permlane32_swap(x1, y1, false, false);            \
      pw[c][0] = r0[0]; pw[c][1] = r1[0]; pw[c][2] = r0[1]; pw[c][3] = r1[1];       \
    }
    PACK_CHUNK(0, s0, 0)
    PACK_CHUNK(1, s0, 8)
    PACK_CHUNK(2, s1, 0)
    PACK_CHUNK(3, s1, 8)
#undef PACK_CHUNK

    __builtin_amdgcn_s_setprio(1);
#pragma unroll
    for (int c = 0; c < 4; ++c) {
      bf16x8 pf = *(const bf16x8*)&pw[c];
      bf16x8 va0 = *(const bf16x8*)&Vt[buf][q31]     [((2 * c + hi) ^ qx) * 8];
      bf16x8 va1 = *(const bf16x8*)&Vt[buf][q31 + 32][((2 * c + hi) ^ qx) * 8];
      o0 = MFMA32_BF16(va0, pf, o0);
      o1 = MFMA32_BF16(va1, pf, o1);
    }
    __builtin_amdgcn_s_setprio(0);
  };

  STAGE(0, 0);
  __syncthreads();

  for (int it = 0; it < 32; it += 2) {
    STAGE((it + 1) * 64, 1);
    COMPUTE(std::integral_constant<int, 0>{});
    __syncthreads();
    if (it + 2 < 32) STAGE((it + 2) * 64, 0);
    COMPUTE(std::integral_constant<int, 1>{});
    __syncthreads();
  }

  f32x16 lt = la0 + la1;
  float lsum;
  {
    float p0 = (lt[0] + lt[1]) + (lt[2] + lt[3]);
    float p1 = (lt[4] + lt[5]) + (lt[6] + lt[7]);
    float p2 = (lt[8] + lt[9]) + (lt[10] + lt[11]);
    float p3 = (lt[12] + lt[13]) + (lt[14] + lt[15]);
    lsum = (p0 + p1) + (p2 + p3);
  }
  lsum += __shfl_xor(lsum, 32, 64);
  const float linv = 1.f / lsum;
  const int b = bh >> 4, h = bh & 15;
  const int qg = qblk * 128 + wq * 32 + q31;
  bf16_t* orow = out + (size_t)(b * 2048 + qg) * 1024 + h * 64;
#pragma unroll
  for (int rg = 0; rg < 4; ++rg) {
    bf16x4 olo = { (bf16_t)(o0[4 * rg + 0] * linv), (bf16_t)(o0[4 * rg + 1] * linv),
                   (bf16_t)(o0[4 * rg + 2] * linv), (bf16_t)(o0[4 * rg + 3] * linv) };
    *(bf16x4*)(orow + 8 * rg + 4 * hi) = olo;
    bf16x4 ohi = { (bf16_t)(o1[4 * rg + 0] * linv), (bf16_t)(o1[4 * rg + 1] * linv),
                   (bf16_t)(o1[4 * rg + 2] * linv), (bf16_t)(o1[4 * rg + 3] * linv) };
    *(bf16x4*)(orow + 32 + 8 * rg + 4 * hi) = ohi;
  }
}

// ---------------------------------------------------------------------------
extern "C" void kernel_launch(void* const* d_in, const int* in_sizes, int n_in,
                              void* d_out, int out_size, void* d_ws, size_t ws_size,
                              hipStream_t stream) {
  const float* x      = (const float*)d_in[0];
  const float* qkv_w  = (const float*)d_in[1];
  const float* qkv_b  = (const float*)d_in[2];
  const float* out_w  = (const float*)d_in[3];
  const float* out_b  = (const float*)d_in[4];
  const float* ln1_g  = (const float*)d_in[5];
  const float* ln1_b  = (const float*)d_in[6];
  const float* ln2_g  = (const float*)d_in[7];
  const float* ln2_b  = (const float*)d_in[8];
  const float* ffn_w1 = (const float*)d_in[9];
  const float* ffn_b1 = (const float*)d_in[10];
  const float* ffn_w2 = (const float*)d_in[11];
  const float* ffn_b2 = (const float*)d_in[12];
  float* outp = (float*)d_out;

  char* p = (char*)d_ws;
  auto alloc = [&](size_t bytes) { char* r = p; p += bytes; return r; };
  bf16_t* qkvw_t = (bf16_t*)alloc((size_t)3072 * 1024 * 2);
  bf16_t* outw_t = (bf16_t*)alloc((size_t)1024 * 1024 * 2);
  bf16_t* w1_t   = (bf16_t*)alloc((size_t)4096 * 1024 * 2);
  bf16_t* w2_t   = (bf16_t*)alloc((size_t)1024 * 4096 * 2);
  bf16_t* h_bf   = (bf16_t*)alloc((size_t)8192 * 1024 * 2);
  bf16_t* q_buf  = (bf16_t*)alloc((size_t)8192 * 1024 * 2);
  bf16_t* k_buf  = (bf16_t*)alloc((size_t)8192 * 1024 * 2);
  bf16_t* v_buf  = (bf16_t*)alloc((size_t)8192 * 1024 * 2);
  bf16_t* a_bf   = (bf16_t*)alloc((size_t)8192 * 1024 * 2);
  bf16_t* o_bf   = (bf16_t*)alloc((size_t)8192 * 1024 * 2);
  bf16_t* out_bf = (bf16_t*)alloc((size_t)8192 * 1024 * 2);
  bf16_t* t_bf   = (bf16_t*)alloc((size_t)8192 * 4096 * 2);

  sa_transpose4<<<3072, 256, 0, stream>>>(qkv_w, qkvw_t, out_w, outw_t,
                                          ffn_w1, w1_t, ffn_w2, w2_t);

  sa_layernorm<<<8192, 256, 0, stream>>>(x, ln1_g, ln1_b, h_bf);

  sa_gemm6<0><<<dim3(3072 / 128, 8192 / 128), 256, 0, stream>>>(
      h_bf, qkvw_t, qkv_b, 1024, 3072, nullptr, nullptr, nullptr, q_buf, k_buf, v_buf);

  sa_attn32<<<dim3(16, 64), 256, 0, stream>>>(q_buf, k_buf, v_buf, a_bf);

  sa_gemm6<1><<<dim3(1024 / 128, 8192 / 128), 256, 0, stream>>>(
      a_bf, outw_t, out_b, 1024, 1024, nullptr, o_bf, nullptr, nullptr, nullptr, nullptr);

  sa_layernorm_b<<<8192, 256, 0, stream>>>(o_bf, ln2_g, ln2_b, out_bf);

  sa_gemm6<2><<<dim3(4096 / 128, 8192 / 128), 256, 0, stream>>>(
      out_bf, w1_t, ffn_b1, 1024, 4096, nullptr, t_bf, nullptr, nullptr, nullptr, nullptr);

  sa_gemm6<3><<<dim3(1024 / 128, 8192 / 128), 256, 0, stream>>>(
      t_bf, w2_t, ffn_b2, 4096, 1024, outp, nullptr, out_bf, nullptr, nullptr, nullptr);
}

// Round 16
// 364.297 us; speedup vs baseline: 1.5022x; 1.5022x over previous
//
#include <hip/hip_runtime.h>
#include <hip/hip_bf16.h>
#include <math.h>
#include <type_traits>

typedef __bf16 bf16_t;
typedef __bf16 bf16x8 __attribute__((ext_vector_type(8)));
typedef __bf16 bf16x4 __attribute__((ext_vector_type(4)));
typedef float  f32x4  __attribute__((ext_vector_type(4)));
typedef float  f32x16 __attribute__((ext_vector_type(16)));
typedef unsigned int u32x2 __attribute__((ext_vector_type(2)));
typedef unsigned int u32x4 __attribute__((ext_vector_type(4)));

#define MFMA_BF16(a, b, c) __builtin_amdgcn_mfma_f32_16x16x32_bf16(a, b, c, 0, 0, 0)
#define MFMA32_BF16(a, b, c) __builtin_amdgcn_mfma_f32_32x32x16_bf16(a, b, c, 0, 0, 0)

#if __has_builtin(__builtin_amdgcn_exp2f)
__device__ __forceinline__ float fast_exp2(float x) { return __builtin_amdgcn_exp2f(x); }
#else
__device__ __forceinline__ float fast_exp2(float x) { return exp2f(x); }
#endif

// NaN-safe tanh-form GELU: g = v - v/(exp2(k*u)+1), u = v(1+0.044715 v^2).
__device__ __forceinline__ float fast_gelu(float v) {
  const float u = v * (1.f + 0.044715f * v * v);
  const float tt = fast_exp2(2.3022078f * u);
  return v - v / (tt + 1.f);
}

// async global->LDS, 16B per lane; LDS dest is wave-uniform base + lane*16
__device__ __forceinline__ void gload_lds16(const bf16_t* g, bf16_t* l) {
  __builtin_amdgcn_global_load_lds(
      (const __attribute__((address_space(1))) void*)g,
      (__attribute__((address_space(3))) void*)l, 16, 0, 0);
}

// ---------------------------------------------------------------------------
// Merged transpose + fp32 -> bf16 convert for all 4 weights (one launch).
// ---------------------------------------------------------------------------
__global__ __launch_bounds__(256) void sa_transpose4(const float* __restrict__ s0, bf16_t* __restrict__ d0,
                                                     const float* __restrict__ s1, bf16_t* __restrict__ d1,
                                                     const float* __restrict__ s2, bf16_t* __restrict__ d2,
                                                     const float* __restrict__ s3, bf16_t* __restrict__ d3) {
  __shared__ bf16_t tile[64][65];
  const int bid = blockIdx.x;
  const float* in; bf16_t* out; int K, N, local;
  if (bid < 768)       { in = s0; out = d0; K = 1024; N = 3072; local = bid; }
  else if (bid < 1024) { in = s1; out = d1; K = 1024; N = 1024; local = bid - 768; }
  else if (bid < 2048) { in = s2; out = d2; K = 1024; N = 4096; local = bid - 1024; }
  else                 { in = s3; out = d3; K = 4096; N = 1024; local = bid - 2048; }
  const int nx = N >> 6;
  const int n0 = (local % nx) * 64, k0 = (local / nx) * 64;
  const int t = threadIdx.x;
#pragma unroll
  for (int i = 0; i < 16; ++i) {
    int idx = t + i * 256;
    int r = idx >> 6, c = idx & 63;
    tile[r][c] = (bf16_t)in[(size_t)(k0 + r) * N + n0 + c];
  }
  __syncthreads();
#pragma unroll
  for (int i = 0; i < 16; ++i) {
    int idx = t + i * 256;
    int r = idx >> 6, c = idx & 63;
    out[(size_t)(n0 + r) * K + k0 + c] = tile[c][r];
  }
}

// ---------------------------------------------------------------------------
// LayerNorm over D=1024 (fp32 input), one block per row. bf16 out.
// ---------------------------------------------------------------------------
__global__ __launch_bounds__(256) void sa_layernorm(const float* __restrict__ in,
                                                    const float* __restrict__ gamma,
                                                    const float* __restrict__ beta,
                                                    bf16_t* __restrict__ out_bf) {
  const int row = blockIdx.x, t = threadIdx.x;
  const float4 v = *(const float4*)(in + (size_t)row * 1024 + t * 4);
  float s  = v.x + v.y + v.z + v.w;
  float ss = v.x * v.x + v.y * v.y + v.z * v.z + v.w * v.w;
#pragma unroll
  for (int m = 1; m < 64; m <<= 1) {
    s  += __shfl_xor(s, m, 64);
    ss += __shfl_xor(ss, m, 64);
  }
  __shared__ float red[8];
  const int w = t >> 6, lane = t & 63;
  if (lane == 0) { red[w] = s; red[4 + w] = ss; }
  __syncthreads();
  s  = red[0] + red[1] + red[2] + red[3];
  ss = red[4] + red[5] + red[6] + red[7];
  const float mu   = s * (1.f / 1024.f);
  const float rstd = rsqrtf(ss * (1.f / 1024.f) - mu * mu + 1e-5f);
  const float4 gv = *(const float4*)(gamma + t * 4);
  const float4 bv = *(const float4*)(beta + t * 4);
  bf16x4 ob = { (bf16_t)((v.x - mu) * rstd * gv.x + bv.x),
                (bf16_t)((v.y - mu) * rstd * gv.y + bv.y),
                (bf16_t)((v.z - mu) * rstd * gv.z + bv.z),
                (bf16_t)((v.w - mu) * rstd * gv.w + bv.w) };
  *(bf16x4*)(out_bf + (size_t)row * 1024 + t * 4) = ob;
}

// ---------------------------------------------------------------------------
// LayerNorm over D=1024 (bf16 input), one block per row. bf16 out.
// ---------------------------------------------------------------------------
__global__ __launch_bounds__(256) void sa_layernorm_b(const bf16_t* __restrict__ in,
                                                      const float* __restrict__ gamma,
                                                      const float* __restrict__ beta,
                                                      bf16_t* __restrict__ out_bf) {
  const int row = blockIdx.x, t = threadIdx.x;
  const bf16x4 iv = *(const bf16x4*)(in + (size_t)row * 1024 + t * 4);
  const float v0 = (float)iv[0], v1 = (float)iv[1], v2 = (float)iv[2], v3 = (float)iv[3];
  float s  = v0 + v1 + v2 + v3;
  float ss = v0 * v0 + v1 * v1 + v2 * v2 + v3 * v3;
#pragma unroll
  for (int m = 1; m < 64; m <<= 1) {
    s  += __shfl_xor(s, m, 64);
    ss += __shfl_xor(ss, m, 64);
  }
  __shared__ float red[8];
  const int w = t >> 6, lane = t & 63;
  if (lane == 0) { red[w] = s; red[4 + w] = ss; }
  __syncthreads();
  s  = red[0] + red[1] + red[2] + red[3];
  ss = red[4] + red[5] + red[6] + red[7];
  const float mu   = s * (1.f / 1024.f);
  const float rstd = rsqrtf(ss * (1.f / 1024.f) - mu * mu + 1e-5f);
  const float4 gv = *(const float4*)(gamma + t * 4);
  const float4 bv = *(const float4*)(beta + t * 4);
  bf16x4 ob = { (bf16_t)((v0 - mu) * rstd * gv.x + bv.x),
                (bf16_t)((v1 - mu) * rstd * gv.y + bv.y),
                (bf16_t)((v2 - mu) * rstd * gv.z + bv.z),
                (bf16_t)((v3 - mu) * rstd * gv.w + bv.w) };
  *(bf16x4*)(out_bf + (size_t)row * 1024 + t * 4) = ob;
}

// ---------------------------------------------------------------------------
// GEMM v4b (r12/r14, best measured): 2-phase schedule + 8x8 supertile XCD
// decode + unroll-2 compile-time buffer. 128x128, BK=64, 4 waves, 64KB LDS,
// 2 blk/CU. Zero-conflict XOR swizzle (both sides).
// EPI: 0 = QKV split (Q scaled by 0.125*log2e; V transposed [bh][d][L]),
//      1 = bf16 store, 2 = fast-GELU->bf16, 3 = fp32 store + bf16 residual.
// Requires gridDim.x % 8 == 0 and gridDim.y == 64. NT even.
// ---------------------------------------------------------------------------
template <int EPI>
__global__ __launch_bounds__(256, 2) void sa_gemm4(const bf16_t* __restrict__ A,
                                                   const bf16_t* __restrict__ Bt,
                                                   const float* __restrict__ bias,
                                                   int K, int N,
                                                   float* __restrict__ fout,
                                                   bf16_t* __restrict__ bfout,
                                                   const bf16_t* __restrict__ res,
                                                   bf16_t* __restrict__ qb,
                                                   bf16_t* __restrict__ kb,
                                                   bf16_t* __restrict__ vb) {
  __shared__ __attribute__((aligned(16))) bf16_t As[2][128][64];
  __shared__ __attribute__((aligned(16))) bf16_t Bs[2][128][64];

  const int gx = gridDim.x;
  const int flat = blockIdx.y * gx + blockIdx.x;
  const int c = flat & 7;
  const int local = flat >> 3;
  const int sg = local >> 6;
  const int rem = local & 63;
  const int by = c * 8 + (rem >> 3);
  const int bx = sg * 8 + (rem & 7);

  const int m0 = by * 128, n0 = bx * 128;
  const int t = threadIdx.x;
  const int w = t >> 6, lane = t & 63;
  const int wr = w >> 1, wc = w & 1;
  const int fr = lane & 15, fq = lane >> 4;
  const int swz = fr & 7;
  const int srow = lane >> 3;
  const int scol = ((lane & 7) ^ srow) * 8;
  const int NT = K >> 6;

  const f32x4 fzero = { 0.f, 0.f, 0.f, 0.f };
  f32x4 acc[4][4];
#pragma unroll
  for (int mi = 0; mi < 4; ++mi)
#pragma unroll
    for (int ni = 0; ni < 4; ++ni) acc[mi][ni] = fzero;

  auto stage = [&](int tt, int sb) {
#pragma unroll
    for (int i = 0; i < 4; ++i) {
      const int ch = w * 4 + i;
      const int row = ch * 8 + srow;
      gload_lds16(A  + (size_t)(m0 + row) * K + tt * 64 + scol, &As[sb][ch * 8][0]);
      gload_lds16(Bt + (size_t)(n0 + row) * K + tt * 64 + scol, &Bs[sb][ch * 8][0]);
    }
  };

  auto compute = [&](auto curc) {
    constexpr int cur = decltype(curc)::value;
    bf16x8 af[4][2], bfr[4][2];
#pragma unroll
    for (int mi = 0; mi < 4; ++mi)
#pragma unroll
      for (int kk = 0; kk < 2; ++kk)
        af[mi][kk] = *(const bf16x8*)&As[cur][wr * 64 + mi * 16 + fr][((kk * 4 + fq) ^ swz) * 8];
#pragma unroll
    for (int ni = 0; ni < 4; ++ni)
#pragma unroll
      for (int kk = 0; kk < 2; ++kk)
        bfr[ni][kk] = *(const bf16x8*)&Bs[cur][wc * 64 + ni * 16 + fr][((kk * 4 + fq) ^ swz) * 8];
    __builtin_amdgcn_s_setprio(1);
#pragma unroll
    for (int kk = 0; kk < 2; ++kk)
#pragma unroll
      for (int mi = 0; mi < 4; ++mi)
#pragma unroll
        for (int ni = 0; ni < 4; ++ni)
          acc[mi][ni] = MFMA_BF16(af[mi][kk], bfr[ni][kk], acc[mi][ni]);
    __builtin_amdgcn_s_setprio(0);
  };

  stage(0, 0);
  __syncthreads();

  for (int tt = 0; tt < NT; tt += 2) {
    stage(tt + 1, 1);
    compute(std::integral_constant<int, 0>{});
    __syncthreads();
    if (tt + 2 < NT) stage(tt + 2, 0);
    compute(std::integral_constant<int, 1>{});
    __syncthreads();
  }

#pragma unroll
  for (int ni = 0; ni < 4; ++ni) {
    const int n = n0 + wc * 64 + ni * 16 + fr;
    const float bn = bias[n];
#pragma unroll
    for (int mi = 0; mi < 4; ++mi) {
      const int mbase = m0 + wr * 64 + mi * 16 + fq * 4;
      float vv[4];
#pragma unroll
      for (int r = 0; r < 4; ++r) vv[r] = acc[mi][ni][r] + bn;
      if constexpr (EPI == 0) {
        const int which = n >> 10;
        const int hh = (n >> 6) & 15;
        const int d = n & 63;
        const int b = mbase >> 11, l = mbase & 2047;
        if (which == 0) {
#pragma unroll
          for (int r = 0; r < 4; ++r)
            qb[((size_t)(b * 16 + hh) * 2048 + l + r) * 64 + d] =
                (bf16_t)(vv[r] * (0.125f * 1.44269504088896340736f));
        } else if (which == 1) {
#pragma unroll
          for (int r = 0; r < 4; ++r)
            kb[((size_t)(b * 16 + hh) * 2048 + l + r) * 64 + d] = (bf16_t)vv[r];
        } else {
          bf16x4 pv = { (bf16_t)vv[0], (bf16_t)vv[1], (bf16_t)vv[2], (bf16_t)vv[3] };
          *(bf16x4*)(vb + ((size_t)(b * 16 + hh) * 64 + d) * 2048 + l) = pv;
        }
      } else if constexpr (EPI == 1) {
#pragma unroll
        for (int r = 0; r < 4; ++r)
          bfout[(size_t)(mbase + r) * N + n] = (bf16_t)vv[r];
      } else if constexpr (EPI == 2) {
#pragma unroll
        for (int r = 0; r < 4; ++r)
          bfout[(size_t)(mbase + r) * N + n] = (bf16_t)fast_gelu(vv[r]);
      } else {
#pragma unroll
        for (int r = 0; r < 4; ++r)
          fout[(size_t)(mbase + r) * N + n] = vv[r] + (float)res[(size_t)(mbase + r) * N + n];
      }
    }
  }
}

// ---------------------------------------------------------------------------
// Flash attention v4 (r14, best measured): 32x32x16 MFMA, in-register P
// (cvt_pk + permlane32_swap), fixed-reference softmax, double-buffered LDS
// via global_load_lds with pre-swizzled source (rule #21), XCD-swizzled grid.
// ---------------------------------------------------------------------------
__global__ __launch_bounds__(256) void sa_attn32(const bf16_t* __restrict__ qb,
                                                 const bf16_t* __restrict__ kb,
                                                 const bf16_t* __restrict__ vb,
                                                 bf16_t* __restrict__ out) {
  __shared__ __attribute__((aligned(16))) bf16_t Ks[2][64][64];   // 16 KB
  __shared__ __attribute__((aligned(16))) bf16_t Vt[2][64][64];   // 16 KB

  const int nwg = gridDim.x * gridDim.y;            // 1024
  const int flat = blockIdx.y * gridDim.x + blockIdx.x;
  const int wg = (flat & 7) * (nwg >> 3) + (flat >> 3);
  const int qblk = wg & 15, bh = wg >> 4;

  const int t = threadIdx.x, wq = t >> 6, lane = t & 63;
  const int q31 = lane & 31, hi = lane >> 5;
  const int qx = q31 & 7;
  const size_t base = (size_t)bh * 2048 * 64;

  const int srow = lane >> 3;
  const int sunit = (lane & 7) ^ srow;

  const bf16_t* qrow = qb + base + (size_t)(qblk * 128 + wq * 32 + q31) * 64 + hi * 8;
  bf16x8 qf[4];
#pragma unroll
  for (int c = 0; c < 4; ++c) qf[c] = *(const bf16x8*)(qrow + c * 16);

  auto STAGE = [&](int kv0, int buf) {
#pragma unroll
    for (int i = 0; i < 2; ++i) {
      const int rb = wq * 16 + i * 8;
      gload_lds16(kb + base + (size_t)(kv0 + rb + srow) * 64 + sunit * 8,
                  &Ks[buf][rb][0]);
      gload_lds16(vb + base + (size_t)(rb + srow) * 2048 + kv0 + sunit * 8,
                  &Vt[buf][rb][0]);
    }
  };

  f32x16 o0, o1, la0, la1;
#pragma unroll
  for (int i = 0; i < 16; ++i) { o0[i] = 0.f; o1[i] = 0.f; la0[i] = 0.f; la1[i] = 0.f; }

  auto COMPUTE = [&](auto bufc) {
    constexpr int buf = decltype(bufc)::value;
    f32x16 s0, s1;
#pragma unroll
    for (int i = 0; i < 16; ++i) { s0[i] = 0.f; s1[i] = 0.f; }
    __builtin_amdgcn_s_setprio(1);
#pragma unroll
    for (int c = 0; c < 4; ++c) {
      bf16x8 ka0 = *(const bf16x8*)&Ks[buf][q31]     [((2 * c + hi) ^ qx) * 8];
      bf16x8 ka1 = *(const bf16x8*)&Ks[buf][q31 + 32][((2 * c + hi) ^ qx) * 8];
      s0 = MFMA32_BF16(ka0, qf[c], s0);
      s1 = MFMA32_BF16(ka1, qf[c], s1);
    }
    __builtin_amdgcn_s_setprio(0);

#pragma unroll
    for (int i = 0; i < 16; ++i) s0[i] = fast_exp2(s0[i]);
#pragma unroll
    for (int i = 0; i < 16; ++i) s1[i] = fast_exp2(s1[i]);
    la0 += s0;
    la1 += s1;

    u32x4 pw[4];
#define PACK_CHUNK(c, SB, off)                                                      \
    {                                                                               \
      unsigned int x0, x1, y0, y1;                                                  \
      asm("v_cvt_pk_bf16_f32 %0, %1, %2" : "=v"(x0) : "v"(SB[off+0]), "v"(SB[off+1])); \
      asm("v_cvt_pk_bf16_f32 %0, %1, %2" : "=v"(x1) : "v"(SB[off+2]), "v"(SB[off+3])); \
      asm("v_cvt_pk_bf16_f32 %0, %1, %2" : "=v"(y0) : "v"(SB[off+4]), "v"(SB[off+5])); \
      asm("v_cvt_pk_bf16_f32 %0, %1, %2" : "=v"(y1) : "v"(SB[off+6]), "v"(SB[off+7])); \
      u32x2 r0 = __builtin_amdgcn_permlane32_swap(x0, y0, false, false);            \
      u32x2 r1 = __builtin_amdgcn_permlane32_swap(x1, y1, false, false);            \
      pw[c][0] = r0[0]; pw[c][1] = r1[0]; pw[c][2] = r0[1]; pw[c][3] = r1[1];       \
    }
    PACK_CHUNK(0, s0, 0)
    PACK_CHUNK(1, s0, 8)
    PACK_CHUNK(2, s1, 0)
    PACK_CHUNK(3, s1, 8)
#undef PACK_CHUNK

    __builtin_amdgcn_s_setprio(1);
#pragma unroll
    for (int c = 0; c < 4; ++c) {
      bf16x8 pf = *(const bf16x8*)&pw[c];
      bf16x8 va0 = *(const bf16x8*)&Vt[buf][q31]     [((2 * c + hi) ^ qx) * 8];
      bf16x8 va1 = *(const bf16x8*)&Vt[buf][q31 + 32][((2 * c + hi) ^ qx) * 8];
      o0 = MFMA32_BF16(va0, pf, o0);
      o1 = MFMA32_BF16(va1, pf, o1);
    }
    __builtin_amdgcn_s_setprio(0);
  };

  STAGE(0, 0);
  __syncthreads();

  for (int it = 0; it < 32; it += 2) {
    STAGE((it + 1) * 64, 1);
    COMPUTE(std::integral_constant<int, 0>{});
    __syncthreads();
    if (it + 2 < 32) STAGE((it + 2) * 64, 0);
    COMPUTE(std::integral_constant<int, 1>{});
    __syncthreads();
  }

  f32x16 lt = la0 + la1;
  float lsum;
  {
    float p0 = (lt[0] + lt[1]) + (lt[2] + lt[3]);
    float p1 = (lt[4] + lt[5]) + (lt[6] + lt[7]);
    float p2 = (lt[8] + lt[9]) + (lt[10] + lt[11]);
    float p3 = (lt[12] + lt[13]) + (lt[14] + lt[15]);
    lsum = (p0 + p1) + (p2 + p3);
  }
  lsum += __shfl_xor(lsum, 32, 64);
  const float linv = 1.f / lsum;
  const int b = bh >> 4, h = bh & 15;
  const int qg = qblk * 128 + wq * 32 + q31;
  bf16_t* orow = out + (size_t)(b * 2048 + qg) * 1024 + h * 64;
#pragma unroll
  for (int rg = 0; rg < 4; ++rg) {
    bf16x4 olo = { (bf16_t)(o0[4 * rg + 0] * linv), (bf16_t)(o0[4 * rg + 1] * linv),
                   (bf16_t)(o0[4 * rg + 2] * linv), (bf16_t)(o0[4 * rg + 3] * linv) };
    *(bf16x4*)(orow + 8 * rg + 4 * hi) = olo;
    bf16x4 ohi = { (bf16_t)(o1[4 * rg + 0] * linv), (bf16_t)(o1[4 * rg + 1] * linv),
                   (bf16_t)(o1[4 * rg + 2] * linv), (bf16_t)(o1[4 * rg + 3] * linv) };
    *(bf16x4*)(orow + 32 + 8 * rg + 4 * hi) = ohi;
  }
}

// ---------------------------------------------------------------------------
extern "C" void kernel_launch(void* const* d_in, const int* in_sizes, int n_in,
                              void* d_out, int out_size, void* d_ws, size_t ws_size,
                              hipStream_t stream) {
  const float* x      = (const float*)d_in[0];
  const float* qkv_w  = (const float*)d_in[1];
  const float* qkv_b  = (const float*)d_in[2];
  const float* out_w  = (const float*)d_in[3];
  const float* out_b  = (const float*)d_in[4];
  const float* ln1_g  = (const float*)d_in[5];
  const float* ln1_b  = (const float*)d_in[6];
  const float* ln2_g  = (const float*)d_in[7];
  const float* ln2_b  = (const float*)d_in[8];
  const float* ffn_w1 = (const float*)d_in[9];
  const float* ffn_b1 = (const float*)d_in[10];
  const float* ffn_w2 = (const float*)d_in[11];
  const float* ffn_b2 = (const float*)d_in[12];
  float* outp = (float*)d_out;

  char* p = (char*)d_ws;
  auto alloc = [&](size_t bytes) { char* r = p; p += bytes; return r; };
  bf16_t* qkvw_t = (bf16_t*)alloc((size_t)3072 * 1024 * 2);
  bf16_t* outw_t = (bf16_t*)alloc((size_t)1024 * 1024 * 2);
  bf16_t* w1_t   = (bf16_t*)alloc((size_t)4096 * 1024 * 2);
  bf16_t* w2_t   = (bf16_t*)alloc((size_t)1024 * 4096 * 2);
  bf16_t* h_bf   = (bf16_t*)alloc((size_t)8192 * 1024 * 2);
  bf16_t* q_buf  = (bf16_t*)alloc((size_t)8192 * 1024 * 2);
  bf16_t* k_buf  = (bf16_t*)alloc((size_t)8192 * 1024 * 2);
  bf16_t* v_buf  = (bf16_t*)alloc((size_t)8192 * 1024 * 2);
  bf16_t* a_bf   = (bf16_t*)alloc((size_t)8192 * 1024 * 2);
  bf16_t* o_bf   = (bf16_t*)alloc((size_t)8192 * 1024 * 2);
  bf16_t* out_bf = (bf16_t*)alloc((size_t)8192 * 1024 * 2);
  bf16_t* t_bf   = (bf16_t*)alloc((size_t)8192 * 4096 * 2);

  sa_transpose4<<<3072, 256, 0, stream>>>(qkv_w, qkvw_t, out_w, outw_t,
                                          ffn_w1, w1_t, ffn_w2, w2_t);

  sa_layernorm<<<8192, 256, 0, stream>>>(x, ln1_g, ln1_b, h_bf);

  sa_gemm4<0><<<dim3(3072 / 128, 8192 / 128), 256, 0, stream>>>(
      h_bf, qkvw_t, qkv_b, 1024, 3072, nullptr, nullptr, nullptr, q_buf, k_buf, v_buf);

  sa_attn32<<<dim3(16, 64), 256, 0, stream>>>(q_buf, k_buf, v_buf, a_bf);

  sa_gemm4<1><<<dim3(1024 / 128, 8192 / 128), 256, 0, stream>>>(
      a_bf, outw_t, out_b, 1024, 1024, nullptr, o_bf, nullptr, nullptr, nullptr, nullptr);

  sa_layernorm_b<<<8192, 256, 0, stream>>>(o_bf, ln2_g, ln2_b, out_bf);

  sa_gemm4<2><<<dim3(4096 / 128, 8192 / 128), 256, 0, stream>>>(
      out_bf, w1_t, ffn_b1, 1024, 4096, nullptr, t_bf, nullptr, nullptr, nullptr, nullptr);

  sa_gemm4<3><<<dim3(1024 / 128, 8192 / 128), 256, 0, stream>>>(
      t_bf, w2_t, ffn_b2, 4096, 1024, outp, nullptr, out_bf, nullptr, nullptr, nullptr);
}